// Round 8
// baseline (2850.963 us; speedup 1.0000x reference)
//
#include <hip/hip_runtime.h>
#include <hip/hip_bf16.h>

typedef unsigned short u16;
typedef unsigned int u32;
typedef unsigned long long u64;
typedef __attribute__((ext_vector_type(8))) short s16x8;
typedef __attribute__((ext_vector_type(4))) float f32x4;

// ---------------- sizes ----------------
// B=128 S=256 E=128 U=512 C=3 ; float inputs are f32, converted to bf16 on device.
//  [0)        cnt    : [2][2][256][2] int        = 8192
//  [8192)     h0ring : [2][4][128][512] bf16     = 1048576   (natural row-major)
//  [1056768)  h1ring : [2][4][128][512] bf16     = 1048576
//  [2105344)  logits : [128][256][3] f32         = 393216
//  ZB = 2498560 (zeroed each launch)
//  [2498560)  X      : [256][128][128] bf16      = 8388608
//  [10887168) Wg     : packed bf16 weights       = 13762560
static constexpr size_t OFF_CNT = 0;
static constexpr size_t OFF_H0  = 8192;
static constexpr size_t OFF_H1  = OFF_H0 + 1048576;
static constexpr size_t OFF_LOG = OFF_H1 + 1048576;
static constexpr size_t ZB      = OFF_LOG + 393216;     // 2498560
static constexpr size_t OFF_X   = ZB;
static constexpr size_t OFF_W   = OFF_X + 8388608;      // 10887168
// packed weight chain offsets in elements (u16):
static constexpr size_t CB_FW0 = 0;
static constexpr size_t CB_FW1 = 1327104;   // 32*64*648
static constexpr size_t CB_BW0 = 3440640;
static constexpr size_t CB_BW1 = 4767744;
// LDS: weight strip (layer-1 worst case 132096B) + 4 waves * 512B transpose scratch
static constexpr unsigned SMEM_BYTES = 64 * 1032 * 2 + 4 * 512;   // 134144

// Flags now count WAVES: 32 WGs x 4 waves = 128 per (layer,t,p).
static constexpr int FLAG_FULL = 128;

__device__ inline u16 f2bu(float f) {
    union { float f; u32 u; } v; v.f = f;
    u32 x = v.u;
    return (u16)((x + 0x7fffu + ((x >> 16) & 1u)) >> 16);  // RNE f32->bf16
}
__device__ inline float sigf(float x) {
    x = fminf(fmaxf(x, -30.f), 30.f);
    return 1.f / (1.f + __expf(-x));
}
__device__ inline float tanh_f(float x) {
    x = fminf(fmaxf(x, -15.f), 15.f);
    float e = __expf(2.f * x);
    return (e - 1.f) / (e + 1.f);
}

// ---------------- phase A kernels ----------------
__global__ void embed_k(const int* __restrict__ tokens, const float2* __restrict__ emb,
                        u32* __restrict__ Xo) {
    int sb = blockIdx.x;               // s*128 + b
    int b = sb & 127, s = sb >> 7;
    int tok = tokens[b * 256 + s];
    float2 v = emb[(size_t)tok * 64 + threadIdx.x];
    Xo[(size_t)sb * 64 + threadIdx.x] = (u32)f2bu(v.x) | ((u32)f2bu(v.y) << 16);
}

// pack [Wr;Wk] (f32 -> bf16) column-reordered (strip-gate-major), +8 row pad.
// dst[nn*(Kc+8) + krow], nn = strip*64 + g*16 + u, src col = g*512 + strip*16 + u
__global__ void wrepack_k(const float* __restrict__ Wr, const float* __restrict__ Wk,
                          u16* __restrict__ dst, int Kc) {
    int e = blockIdx.x * 256 + threadIdx.x;
    int krow = e % Kc;
    int nn = e / Kc;
    if (nn >= 2048) return;
    int i = nn >> 6, n = nn & 63;
    int g = n >> 4, u = n & 15;
    int col = g * 512 + i * 16 + u;
    float v = (krow < 512) ? Wr[(size_t)krow * 2048 + col]
                           : Wk[(size_t)(krow - 512) * 2048 + col];
    dst[(size_t)nn * (Kc + 8) + krow] = f2bu(v);
}

// ---------------- main persistent kernel ----------------
// Protocol (round-8 — round-5 proven core + chain-shortening):
//   WRITER: LDS transpose -> coalesced 8B sc0sc1 WRITE-THROUGH h store ->
//           PER-WAVE vmcnt(0) -> PER-WAVE lane0 RELAXED fetch_add (no barrier
//           on the publish path; flags count to 128).
//   READER: poll flags -> acquire agent fence (buffer_inv) -> cached loads.
//   CHAIN-SHORTENING: work whose inputs are flag-confirmed-old (L1's h0[t],
//   L0's x[t]) is loaded+MFMA'd BEFORE the wait/inv. Pre-inv cached reads of
//   h0[t] are safe when its flag is set: data is at L3 (WT stores precede the
//   flag) and the slot's L2 lines were cleared by the >=3 whole-L2 invs since
//   this WG last touched that ring slot.
__device__ inline void wait2(int* a, int* b) {
    if (threadIdx.x == 0) {
        int spins = 0;
        bool oka = (a == nullptr), okb = (b == nullptr);
        while (!(oka && okb)) {
            if (!oka) oka = __hip_atomic_load(a, __ATOMIC_RELAXED, __HIP_MEMORY_SCOPE_AGENT) >= FLAG_FULL;
            if (!okb) okb = __hip_atomic_load(b, __ATOMIC_RELAXED, __HIP_MEMORY_SCOPE_AGENT) >= FLAG_FULL;
            if (oka && okb) break;
            __builtin_amdgcn_s_sleep(2);
            if (++spins > (1 << 17)) break;   // ~7 ms watchdog
        }
        __builtin_amdgcn_fence(__ATOMIC_ACQUIRE, "agent");   // inv only
    }
    __syncthreads();
}

template <int LAYER>
__device__ __forceinline__ void run_chain(
    const u16* __restrict__ wlds, u16* __restrict__ tlds, const u16* __restrict__ X,
    u16* __restrict__ H0, u16* __restrict__ H1, int* __restrict__ cb,
    float* __restrict__ logits, const float* __restrict__ bptr,
    const float* __restrict__ dW,
    int dir, int p, int strip, int wv, int lane)
{
    constexpr int Kpad = LAYER ? 1032 : 648;
    const int uu   = lane & 15;
    const int qq   = lane >> 4;
    const int rowA = p * 64 + wv * 16 + uu;
    const u16* blds = wlds + (size_t)uu * Kpad + qq * 8;

    float bias[4];
#pragma unroll
    for (int g = 0; g < 4; ++g) bias[g] = bptr[g * 512 + strip * 16 + uu];
    float wd[3] = {0.f, 0.f, 0.f};
    if (LAYER == 1) {
#pragma unroll
        for (int c = 0; c < 3; ++c)
            wd[c] = dW[(size_t)(dir * 512 + strip * 16 + uu) * 3 + c];
    }

    float cst[4] = {0.f, 0.f, 0.f, 0.f};

    for (int t = 0; t < 256; ++t) {
        s16x8 af[16], af2[16], xf[4];
        f32x4 acc[4];
#pragma unroll
        for (int g = 0; g < 4; ++g)
            acc[g] = (f32x4){bias[g], bias[g], bias[g], bias[g]};

        if (LAYER == 0) {
            // ---- pre-wait phase: x load + x·Wk MFMAs (no flag needed) ----
            int tx = dir ? (255 - t) : t;
            const u16* xb = X + (size_t)tx * 16384 + rowA * 128 + qq * 8;
#pragma unroll
            for (int j = 0; j < 4; ++j) xf[j] = *(const s16x8*)(xb + j * 32);
#pragma unroll
            for (int j = 0; j < 4; ++j) {
                s16x8 av = xf[j];
#pragma unroll
                for (int g = 0; g < 4; ++g) {
                    s16x8 bv = *(const s16x8*)(blds + (size_t)g * 16 * Kpad + (16 + j) * 32);
                    acc[g] = __builtin_amdgcn_mfma_f32_16x16x32_bf16(av, bv, acc[g], 0, 0, 0);
                }
            }

            // ---- serial wait: h0[t-1] flag + ring backpressure ----
            int* fa = (t > 0)  ? &cb[(0 * 256 + (t - 1)) * 2 + p] : nullptr;
            int* fb = (t >= 4) ? &cb[(256 + (t - 4)) * 2 + p]     : nullptr;
            if (fa || fb) wait2(fa, fb);

            // ---- post-inv: h0[t-1] gather + recurrent MFMAs ----
            const u16* pa = H0 + ((t - 1) & 3) * 65536 + (size_t)rowA * 512 + qq * 8;
#pragma unroll
            for (int i = 0; i < 16; ++i) af[i] = *(const s16x8*)(pa + i * 32);
#pragma unroll
            for (int kt = 0; kt < 16; ++kt) {
                s16x8 av = af[kt];
#pragma unroll
                for (int g = 0; g < 4; ++g) {
                    s16x8 bv = *(const s16x8*)(blds + (size_t)g * 16 * Kpad + kt * 32);
                    acc[g] = __builtin_amdgcn_mfma_f32_16x16x32_bf16(av, bv, acc[g], 0, 0, 0);
                }
            }
        } else {
            int* fa = &cb[(0 * 256 + t) * 2 + p];
            int* fb = (t > 0) ? &cb[(256 + (t - 1)) * 2 + p] : nullptr;

            // ---- per-wave non-blocking check of h0[t] flag (L0 runs ahead:
            //      almost always set in steady state) ----
            int fv = 0;
            if (lane == 0)
                fv = __hip_atomic_load(fa, __ATOMIC_RELAXED, __HIP_MEMORY_SCOPE_AGENT);
            fv = __shfl(fv, 0);
            const bool h0r = (fv >= FLAG_FULL);

            const u16* pb = H0 + (t & 3) * 65536 + (size_t)rowA * 512 + qq * 8;
            if (h0r) {
                // ---- pre-wait phase: h0[t] gather + h0·Wk MFMAs, overlapped
                //      with waiting on the h1[t-1] serial flag ----
#pragma unroll
                for (int i = 0; i < 16; ++i) af2[i] = *(const s16x8*)(pb + i * 32);
#pragma unroll
                for (int kt = 0; kt < 16; ++kt) {
                    s16x8 av = af2[kt];
#pragma unroll
                    for (int g = 0; g < 4; ++g) {
                        s16x8 bv = *(const s16x8*)(blds + (size_t)g * 16 * Kpad + (16 + kt) * 32);
                        acc[g] = __builtin_amdgcn_mfma_f32_16x16x32_bf16(av, bv, acc[g], 0, 0, 0);
                    }
                }
            }

            // ---- serial wait (fa instant if h0r; one inv; block barrier) ----
            wait2(fa, fb);

            // ---- post-inv: h1[t-1] gather + recurrent MFMAs ----
            const u16* pa = H1 + ((t - 1) & 3) * 65536 + (size_t)rowA * 512 + qq * 8;
#pragma unroll
            for (int i = 0; i < 16; ++i) af[i] = *(const s16x8*)(pa + i * 32);
#pragma unroll
            for (int kt = 0; kt < 16; ++kt) {
                s16x8 av = af[kt];
#pragma unroll
                for (int g = 0; g < 4; ++g) {
                    s16x8 bv = *(const s16x8*)(blds + (size_t)g * 16 * Kpad + kt * 32);
                    acc[g] = __builtin_amdgcn_mfma_f32_16x16x32_bf16(av, bv, acc[g], 0, 0, 0);
                }
            }
            if (!h0r) {   // slow path: h0 flag wasn't set pre-wait
#pragma unroll
                for (int i = 0; i < 16; ++i) af2[i] = *(const s16x8*)(pb + i * 32);
#pragma unroll
                for (int kt = 0; kt < 16; ++kt) {
                    s16x8 av = af2[kt];
#pragma unroll
                    for (int g = 0; g < 4; ++g) {
                        s16x8 bv = *(const s16x8*)(blds + (size_t)g * 16 * Kpad + (16 + kt) * 32);
                        acc[g] = __builtin_amdgcn_mfma_f32_16x16x32_bf16(av, bv, acc[g], 0, 0, 0);
                    }
                }
            }
        }

        // LSTM epilogue
        u16* Hout = (LAYER == 0) ? H0 + (t & 3) * 65536 : H1 + (t & 3) * 65536;
        float hv[4];
        u32 hb[4];
#pragma unroll
        for (int j = 0; j < 4; ++j) {
            float iv = sigf(acc[0][j]);
            float fv2 = sigf(acc[1][j]);
            float gv = tanh_f(acc[2][j]);
            float ov = sigf(acc[3][j]);
            float cj = fv2 * cst[j] + iv * gv;
            cst[j] = cj;
            float h = ov * tanh_f(cj);
            hv[j] = h;
            hb[j] = (u32)f2bu(h);
        }

        // per-wave 16x16 u16 transpose through wave-private LDS scratch, then
        // ONE coalesced 8B write-through store per lane
        u16* tw = tlds + wv * 256;
#pragma unroll
        for (int j = 0; j < 4; ++j)
            tw[(qq * 4 + j) * 16 + uu] = (u16)hb[j];
        asm volatile("s_waitcnt lgkmcnt(0)" ::: "memory");
        __builtin_amdgcn_sched_barrier(0);
        {
            const int r  = lane >> 2;       // 0..15 row within wave tile
            const int cq = lane & 3;        // 4-col group
            u64 v = *(const u64*)(tw + r * 16 + cq * 4);
            u16* dst = Hout + (size_t)(p * 64 + wv * 16 + r) * 512 + strip * 16 + cq * 4;
            asm volatile("global_store_dwordx2 %0, %1, off sc0 sc1"
                         :: "v"(dst), "v"(v) : "memory");
        }

        // PER-WAVE publish: drain this wave's WT stores, lane0 increments.
        // No block barrier on the publish path (flags count to 128).
        asm volatile("s_waitcnt vmcnt(0)" ::: "memory");
        if (lane == 0)
            __hip_atomic_fetch_add(&cb[(LAYER * 256 + t) * 2 + p], 1,
                                   __ATOMIC_RELAXED, __HIP_MEMORY_SCOPE_AGENT);

        if (LAYER == 1) {   // fused dense AFTER the publish: atomics drain in
                            // the background (consumed only by softmax_k)
            int s_out = dir ? (255 - t) : t;
            const int rowC = p * 64 + wv * 16 + qq * 4;
#pragma unroll
            for (int j = 0; j < 4; ++j) {
#pragma unroll
                for (int c = 0; c < 3; ++c) {
                    float v = hv[j] * wd[c];
                    v += __shfl_xor(v, 1);
                    v += __shfl_xor(v, 2);
                    v += __shfl_xor(v, 4);
                    v += __shfl_xor(v, 8);
                    if (uu == 0)
                        atomicAdd(&logits[((size_t)(rowC + j) * 256 + s_out) * 3 + c], v);
                }
            }
        }
    }
    // ensure trailing background atomics/stores are complete before endpgm
    asm volatile("s_waitcnt vmcnt(0)" ::: "memory");
}

__global__ void __launch_bounds__(256, 1)
lstm_engine(const u16* __restrict__ Wg, const u16* __restrict__ X,
            u16* __restrict__ h0ring, u16* __restrict__ h1ring,
            int* __restrict__ cnt, float* __restrict__ logits,
            const float* __restrict__ bf0, const float* __restrict__ bf1,
            const float* __restrict__ bb0, const float* __restrict__ bb1,
            const float* __restrict__ dW) {
    extern __shared__ u16 wlds[];
    const int tid = threadIdx.x;
    const int bid = blockIdx.x;
    const int dir   = bid >> 7;        // 0 fw, 1 bw
    const int rr    = bid & 127;
    const int layer = rr >> 6;         // 0 or 1
    const int q     = rr & 63;
    const int strip = q >> 1;          // 0..31 (16 hidden units each)
    const int p     = q & 1;           // row block (64 rows)
    const int wv    = tid >> 6;        // wave 0..3
    const int lane  = tid & 63;

    const int Kc   = layer ? 1024 : 640;
    const int Kpad = Kc + 8;
    const size_t cbase = layer ? (dir ? CB_BW1 : CB_FW1) : (dir ? CB_BW0 : CB_FW0);
    const u16* wsrc = Wg + cbase + (size_t)strip * 64 * Kpad;

    {   // stage weight strip into LDS (one time)
        const uint4* s4 = (const uint4*)wsrc;
        uint4* d4 = (uint4*)wlds;
        const int n16 = (64 * Kpad) / 8;
        for (int j = tid; j < n16; j += 256) d4[j] = s4[j];
    }
    __syncthreads();

    u16* tlds = wlds + (size_t)64 * Kpad;   // 4 waves x 512B transpose scratch

    u16* H0 = h0ring + (size_t)dir * (4 * 65536);
    u16* H1 = h1ring + (size_t)dir * (4 * 65536);
    int* cb = cnt + dir * (2 * 256 * 2);   // [layer][t][p]
    const float* bptr = layer ? (dir ? bb1 : bf1) : (dir ? bb0 : bf0);

    if (layer == 0)
        run_chain<0>(wlds, tlds, X, H0, H1, cb, logits, bptr, dW, dir, p, strip, wv, lane);
    else
        run_chain<1>(wlds, tlds, X, H0, H1, cb, logits, bptr, dW, dir, p, strip, wv, lane);
}

__global__ void softmax_k(const float* __restrict__ logits, const float* __restrict__ db,
                          float* __restrict__ out) {
    int idx = blockIdx.x * 256 + threadIdx.x;   // b*256+s
    float l0 = logits[(size_t)idx * 3 + 0] + db[0];
    float l1 = logits[(size_t)idx * 3 + 1] + db[1];
    float l2 = logits[(size_t)idx * 3 + 2] + db[2];
    float m = fmaxf(l0, fmaxf(l1, l2));
    float e0 = __expf(l0 - m), e1 = __expf(l1 - m), e2 = __expf(l2 - m);
    float r = 1.f / (e0 + e1 + e2);
    out[(size_t)idx * 3 + 0] = e0 * r;
    out[(size_t)idx * 3 + 1] = e1 * r;
    out[(size_t)idx * 3 + 2] = e2 * r;
}

extern "C" void kernel_launch(void* const* d_in, const int* in_sizes, int n_in,
                              void* d_out, int out_size, void* d_ws, size_t ws_size,
                              hipStream_t stream) {
    (void)in_sizes; (void)n_in; (void)out_size; (void)ws_size;
    const int*    tokens = (const int*)d_in[0];
    const float2* emb    = (const float2*)d_in[1];
    const float* fw0_Wk = (const float*)d_in[2];
    const float* fw0_Wr = (const float*)d_in[3];
    const float* fw0_b  = (const float*)d_in[4];
    const float* fw1_Wk = (const float*)d_in[5];
    const float* fw1_Wr = (const float*)d_in[6];
    const float* fw1_b  = (const float*)d_in[7];
    const float* bw0_Wk = (const float*)d_in[8];
    const float* bw0_Wr = (const float*)d_in[9];
    const float* bw0_b  = (const float*)d_in[10];
    const float* bw1_Wk = (const float*)d_in[11];
    const float* bw1_Wr = (const float*)d_in[12];
    const float* bw1_b  = (const float*)d_in[13];
    const float* dW     = (const float*)d_in[14];
    const float* db     = (const float*)d_in[15];

    char* ws = (char*)d_ws;
    int*   cnt = (int*)(ws + OFF_CNT);
    u16*   H0  = (u16*)(ws + OFF_H0);
    u16*   H1  = (u16*)(ws + OFF_H1);
    float* lg  = (float*)(ws + OFF_LOG);
    u32*   Xw  = (u32*)(ws + OFF_X);
    const u16* Xr = (const u16*)(ws + OFF_X);
    u16*   Wg  = (u16*)(ws + OFF_W);
    const u16* Wgc = Wg;

    hipMemsetAsync(ws, 0, ZB, stream);
    embed_k<<<32768, 64, 0, stream>>>(tokens, emb, Xw);
    wrepack_k<<<5120, 256, 0, stream>>>(fw0_Wr, fw0_Wk, Wg + CB_FW0, 640);
    wrepack_k<<<8192, 256, 0, stream>>>(fw1_Wr, fw1_Wk, Wg + CB_FW1, 1024);
    wrepack_k<<<5120, 256, 0, stream>>>(bw0_Wr, bw0_Wk, Wg + CB_BW0, 640);
    wrepack_k<<<8192, 256, 0, stream>>>(bw1_Wr, bw1_Wk, Wg + CB_BW1, 1024);

    hipFuncSetAttribute((const void*)lstm_engine,
                        hipFuncAttributeMaxDynamicSharedMemorySize, SMEM_BYTES);
    void* args[] = { (void*)&Wgc, (void*)&Xr, (void*)&H0, (void*)&H1, (void*)&cnt,
                     (void*)&lg, (void*)&fw0_b, (void*)&fw1_b, (void*)&bw0_b,
                     (void*)&bw1_b, (void*)&dW };
    hipLaunchCooperativeKernel((const void*)lstm_engine, dim3(256), dim3(256),
                               args, SMEM_BYTES, stream);

    softmax_k<<<128, 256, 0, stream>>>(lg, db, (float*)d_out);
}

// Round 9
// 2589.374 us; speedup vs baseline: 1.1010x; 1.1010x over previous
//
#include <hip/hip_runtime.h>
#include <hip/hip_bf16.h>

typedef unsigned short u16;
typedef unsigned int u32;
typedef unsigned long long u64;
typedef __attribute__((ext_vector_type(8))) short s16x8;
typedef __attribute__((ext_vector_type(4))) float f32x4;

// ---------------- sizes ----------------
// B=128 S=256 E=128 U=512 C=3 ; float inputs are f32, converted to bf16 on device.
//  [0)        tags   : [2][2][256][2][32] int    = 262144  (per-WG publish tags)
//  [262144)   h0ring : [2][4][128][512] bf16     = 1048576 (natural row-major)
//  [1310720)  h1ring : [2][4][128][512] bf16     = 1048576
//  [2359296)  logits : [128][256][3] f32         = 393216
//  ZB = 2752512 (zeroed each launch)
//  [2752512)  X      : [256][128][128] bf16      = 8388608
//  [11141120) Wg     : packed bf16 weights       = 13762560
static constexpr size_t OFF_CNT = 0;
static constexpr size_t OFF_H0  = 262144;
static constexpr size_t OFF_H1  = OFF_H0 + 1048576;
static constexpr size_t OFF_LOG = OFF_H1 + 1048576;
static constexpr size_t ZB      = OFF_LOG + 393216;     // 2752512
static constexpr size_t OFF_X   = ZB;
static constexpr size_t OFF_W   = OFF_X + 8388608;      // 11141120
// packed weight chain offsets in elements (u16):
static constexpr size_t CB_FW0 = 0;
static constexpr size_t CB_FW1 = 1327104;   // 32*64*648
static constexpr size_t CB_BW0 = 3440640;
static constexpr size_t CB_BW1 = 4767744;
// LDS: weight strip (layer-1 worst case 132096B) + 4 waves * 512B transpose scratch
static constexpr unsigned SMEM_BYTES = 64 * 1032 * 2 + 4 * 512;   // 134144

__device__ inline u16 f2bu(float f) {
    union { float f; u32 u; } v; v.f = f;
    u32 x = v.u;
    return (u16)((x + 0x7fffu + ((x >> 16) & 1u)) >> 16);  // RNE f32->bf16
}
__device__ inline float sigf(float x) {
    x = fminf(fmaxf(x, -30.f), 30.f);
    return 1.f / (1.f + __expf(-x));
}
__device__ inline float tanh_f(float x) {
    x = fminf(fmaxf(x, -15.f), 15.f);
    float e = __expf(2.f * x);
    return (e - 1.f) / (e + 1.f);
}

// ---------------- phase A kernels ----------------
__global__ void embed_k(const int* __restrict__ tokens, const float2* __restrict__ emb,
                        u32* __restrict__ Xo) {
    int sb = blockIdx.x;               // s*128 + b
    int b = sb & 127, s = sb >> 7;
    int tok = tokens[b * 256 + s];
    float2 v = emb[(size_t)tok * 64 + threadIdx.x];
    Xo[(size_t)sb * 64 + threadIdx.x] = (u32)f2bu(v.x) | ((u32)f2bu(v.y) << 16);
}

// pack [Wr;Wk] (f32 -> bf16) column-reordered (strip-gate-major), +8 row pad.
// dst[nn*(Kc+8) + krow], nn = strip*64 + g*16 + u, src col = g*512 + strip*16 + u
__global__ void wrepack_k(const float* __restrict__ Wr, const float* __restrict__ Wk,
                          u16* __restrict__ dst, int Kc) {
    int e = blockIdx.x * 256 + threadIdx.x;
    int krow = e % Kc;
    int nn = e / Kc;
    if (nn >= 2048) return;
    int i = nn >> 6, n = nn & 63;
    int g = n >> 4, u = n & 15;
    int col = g * 512 + i * 16 + u;
    float v = (krow < 512) ? Wr[(size_t)krow * 2048 + col]
                           : Wk[(size_t)(krow - 512) * 2048 + col];
    dst[(size_t)nn * (Kc + 8) + krow] = f2bu(v);
}

// ---------------- main persistent kernel ----------------
// Protocol (round-9 — round-5 proven core + de-contended publish):
//   WRITER: LDS transpose -> coalesced 8B sc0sc1 WRITE-THROUGH h store ->
//           vmcnt(0) -> barrier -> tid0 RELAXED atomic STORE of 1 to the WG's
//           OWN tag word (replaces 32 serialized fetch_adds on one cacheline).
//   READER: wave0 polls the 32 tags of each needed group LANE-PARALLEL
//           (ballot until all set) -> acquire agent fence (buffer_inv) ->
//           plain cached batched loads (proven refill path).
// Tag groups: ta = 32 words; tb = 32 words (or null). Lanes 0-31 poll ta,
// lanes 32-63 poll tb.
__device__ inline void wait_tags(const int* ta, const int* tb) {
    const int tid = threadIdx.x;
    if (tid < 64) {
        const int lane = tid;
        const int* mine = nullptr;
        if (lane < 32) { if (ta) mine = ta + lane; }
        else           { if (tb) mine = tb + (lane - 32); }
        bool done = (mine == nullptr);
        int spins = 0;
        for (;;) {
            if (!done)
                done = __hip_atomic_load(mine, __ATOMIC_RELAXED,
                                         __HIP_MEMORY_SCOPE_AGENT) != 0;
            if (__ballot(done) == ~0ull) break;
            __builtin_amdgcn_s_sleep(2);
            if (++spins > (1 << 17)) break;   // ~7 ms watchdog
        }
        __builtin_amdgcn_fence(__ATOMIC_ACQUIRE, "agent");   // inv only
    }
    __syncthreads();
}

template <int LAYER>
__device__ __forceinline__ void run_chain(
    const u16* __restrict__ wlds, u16* __restrict__ tlds, const u16* __restrict__ X,
    u16* __restrict__ H0, u16* __restrict__ H1, int* __restrict__ cb,
    float* __restrict__ logits, const float* __restrict__ bptr,
    const float* __restrict__ dW,
    int dir, int p, int strip, int wv, int lane)
{
    constexpr int Kpad = LAYER ? 1032 : 648;
    const int tid  = threadIdx.x;
    const int uu   = lane & 15;
    const int qq   = lane >> 4;
    const int rowA = p * 64 + wv * 16 + uu;
    const u16* blds = wlds + (size_t)uu * Kpad + qq * 8;

    float bias[4];
#pragma unroll
    for (int g = 0; g < 4; ++g) bias[g] = bptr[g * 512 + strip * 16 + uu];
    float wd[3] = {0.f, 0.f, 0.f};
    if (LAYER == 1) {
#pragma unroll
        for (int c = 0; c < 3; ++c)
            wd[c] = dW[(size_t)(dir * 512 + strip * 16 + uu) * 3 + c];
    }

    float cst[4] = {0.f, 0.f, 0.f, 0.f};

    for (int t = 0; t < 256; ++t) {
        s16x8 af[16], af2[16], xf[4];

        if (LAYER == 0) {
            // X prefetch into VGPRs BEFORE the wait (read-only; survives the inv)
            int tx = dir ? (255 - t) : t;
            const u16* xb = X + (size_t)tx * 16384 + rowA * 128 + qq * 8;
#pragma unroll
            for (int j = 0; j < 4; ++j) xf[j] = *(const s16x8*)(xb + j * 32);

            // wait: h0[t-1] tag group + ring backpressure tag group (L1 t-4)
            const int* ta = (t > 0)  ? cb + (((t - 1) * 2 + p) << 5) : nullptr;
            const int* tb = (t >= 4) ? cb + (((256 + (t - 4)) * 2 + p) << 5) : nullptr;
            if (ta || tb) wait_tags(ta, tb);

            // batched plain loads of all 16 h0_prev fragments (one latency round)
            const u16* pa = H0 + ((t - 1) & 3) * 65536 + (size_t)rowA * 512 + qq * 8;
#pragma unroll
            for (int i = 0; i < 16; ++i) af[i] = *(const s16x8*)(pa + i * 32);
        } else {
            // wait: h0[t] tag group + h1[t-1] tag group, single acquire fence
            const int* ta = cb + ((t * 2 + p) << 5);
            const int* tb = (t > 0) ? cb + (((256 + (t - 1)) * 2 + p) << 5) : nullptr;
            wait_tags(ta, tb);

            const u16* pb = H0 + (t & 3) * 65536 + (size_t)rowA * 512 + qq * 8;
#pragma unroll
            for (int i = 0; i < 16; ++i) af2[i] = *(const s16x8*)(pb + i * 32);
            const u16* pa = H1 + ((t - 1) & 3) * 65536 + (size_t)rowA * 512 + qq * 8;
#pragma unroll
            for (int i = 0; i < 16; ++i) af[i] = *(const s16x8*)(pa + i * 32);
        }

        f32x4 acc[4];
#pragma unroll
        for (int g = 0; g < 4; ++g)
            acc[g] = (f32x4){bias[g], bias[g], bias[g], bias[g]};

        // MFMA order identical to the proven kernels: kt ascending, gate inner
#pragma unroll
        for (int kt = 0; kt < 16; ++kt) {
            s16x8 av = af[kt];
#pragma unroll
            for (int g = 0; g < 4; ++g) {
                s16x8 bv = *(const s16x8*)(blds + (size_t)g * 16 * Kpad + kt * 32);
                acc[g] = __builtin_amdgcn_mfma_f32_16x16x32_bf16(av, bv, acc[g], 0, 0, 0);
            }
        }
        if (LAYER == 0) {
#pragma unroll
            for (int j = 0; j < 4; ++j) {
                s16x8 av = xf[j];
#pragma unroll
                for (int g = 0; g < 4; ++g) {
                    s16x8 bv = *(const s16x8*)(blds + (size_t)g * 16 * Kpad + (16 + j) * 32);
                    acc[g] = __builtin_amdgcn_mfma_f32_16x16x32_bf16(av, bv, acc[g], 0, 0, 0);
                }
            }
        } else {
#pragma unroll
            for (int kt = 0; kt < 16; ++kt) {
                s16x8 av = af2[kt];
#pragma unroll
                for (int g = 0; g < 4; ++g) {
                    s16x8 bv = *(const s16x8*)(blds + (size_t)g * 16 * Kpad + (16 + kt) * 32);
                    acc[g] = __builtin_amdgcn_mfma_f32_16x16x32_bf16(av, bv, acc[g], 0, 0, 0);
                }
            }
        }

        // LSTM epilogue
        u16* Hout = (LAYER == 0) ? H0 + (t & 3) * 65536 : H1 + (t & 3) * 65536;
        float hv[4];
        u32 hb[4];
#pragma unroll
        for (int j = 0; j < 4; ++j) {
            float iv = sigf(acc[0][j]);
            float fv = sigf(acc[1][j]);
            float gv = tanh_f(acc[2][j]);
            float ov = sigf(acc[3][j]);
            float cj = fv * cst[j] + iv * gv;
            cst[j] = cj;
            float h = ov * tanh_f(cj);
            hv[j] = h;
            hb[j] = (u32)f2bu(h);
        }

        // per-wave 16x16 u16 transpose through wave-private LDS scratch, then
        // ONE coalesced 8B write-through store per lane
        u16* tw = tlds + wv * 256;
#pragma unroll
        for (int j = 0; j < 4; ++j)
            tw[(qq * 4 + j) * 16 + uu] = (u16)hb[j];
        asm volatile("s_waitcnt lgkmcnt(0)" ::: "memory");
        __builtin_amdgcn_sched_barrier(0);
        {
            const int r  = lane >> 2;       // 0..15 row within wave tile
            const int cq = lane & 3;        // 4-col group
            u64 v = *(const u64*)(tw + r * 16 + cq * 4);
            u16* dst = Hout + (size_t)(p * 64 + wv * 16 + r) * 512 + strip * 16 + cq * 4;
            asm volatile("global_store_dwordx2 %0, %1, off sc0 sc1"
                         :: "v"(dst), "v"(v) : "memory");
        }

        // drain h stores, block barrier, then publish via UNCONTENDED tag store
        asm volatile("s_waitcnt vmcnt(0)" ::: "memory");
        __syncthreads();
        if (tid == 0)
            __hip_atomic_store(cb + (((LAYER * 256 + t) * 2 + p) << 5) + strip, 1,
                               __ATOMIC_RELAXED, __HIP_MEMORY_SCOPE_AGENT);

        if (LAYER == 1) {   // fused dense AFTER the publish: atomics drain in
                            // the background (consumed only by softmax_k)
            int s_out = dir ? (255 - t) : t;
            const int rowC = p * 64 + wv * 16 + qq * 4;
#pragma unroll
            for (int j = 0; j < 4; ++j) {
#pragma unroll
                for (int c = 0; c < 3; ++c) {
                    float v = hv[j] * wd[c];
                    v += __shfl_xor(v, 1);
                    v += __shfl_xor(v, 2);
                    v += __shfl_xor(v, 4);
                    v += __shfl_xor(v, 8);
                    if (uu == 0)
                        atomicAdd(&logits[((size_t)(rowC + j) * 256 + s_out) * 3 + c], v);
                }
            }
        }
    }
    // ensure trailing background atomics/stores are complete before endpgm
    asm volatile("s_waitcnt vmcnt(0)" ::: "memory");
}

__global__ void __launch_bounds__(256, 1)
lstm_engine(const u16* __restrict__ Wg, const u16* __restrict__ X,
            u16* __restrict__ h0ring, u16* __restrict__ h1ring,
            int* __restrict__ cnt, float* __restrict__ logits,
            const float* __restrict__ bf0, const float* __restrict__ bf1,
            const float* __restrict__ bb0, const float* __restrict__ bb1,
            const float* __restrict__ dW) {
    extern __shared__ u16 wlds[];
    const int tid = threadIdx.x;
    const int bid = blockIdx.x;
    const int dir   = bid >> 7;        // 0 fw, 1 bw
    const int rr    = bid & 127;
    const int layer = rr >> 6;         // 0 or 1
    const int q     = rr & 63;
    const int strip = q >> 1;          // 0..31 (16 hidden units each)
    const int p     = q & 1;           // row block (64 rows)
    const int wv    = tid >> 6;        // wave 0..3
    const int lane  = tid & 63;

    const int Kc   = layer ? 1024 : 640;
    const int Kpad = Kc + 8;
    const size_t cbase = layer ? (dir ? CB_BW1 : CB_FW1) : (dir ? CB_BW0 : CB_FW0);
    const u16* wsrc = Wg + cbase + (size_t)strip * 64 * Kpad;

    {   // stage weight strip into LDS (one time)
        const uint4* s4 = (const uint4*)wsrc;
        uint4* d4 = (uint4*)wlds;
        const int n16 = (64 * Kpad) / 8;
        for (int j = tid; j < n16; j += 256) d4[j] = s4[j];
    }
    __syncthreads();

    u16* tlds = wlds + (size_t)64 * Kpad;   // 4 waves x 512B transpose scratch

    u16* H0 = h0ring + (size_t)dir * (4 * 65536);
    u16* H1 = h1ring + (size_t)dir * (4 * 65536);
    int* cb = cnt + dir * (2 * 256 * 2 * 32);   // [layer][t][p][strip]
    const float* bptr = layer ? (dir ? bb1 : bf1) : (dir ? bb0 : bf0);

    if (layer == 0)
        run_chain<0>(wlds, tlds, X, H0, H1, cb, logits, bptr, dW, dir, p, strip, wv, lane);
    else
        run_chain<1>(wlds, tlds, X, H0, H1, cb, logits, bptr, dW, dir, p, strip, wv, lane);
}

__global__ void softmax_k(const float* __restrict__ logits, const float* __restrict__ db,
                          float* __restrict__ out) {
    int idx = blockIdx.x * 256 + threadIdx.x;   // b*256+s
    float l0 = logits[(size_t)idx * 3 + 0] + db[0];
    float l1 = logits[(size_t)idx * 3 + 1] + db[1];
    float l2 = logits[(size_t)idx * 3 + 2] + db[2];
    float m = fmaxf(l0, fmaxf(l1, l2));
    float e0 = __expf(l0 - m), e1 = __expf(l1 - m), e2 = __expf(l2 - m);
    float r = 1.f / (e0 + e1 + e2);
    out[(size_t)idx * 3 + 0] = e0 * r;
    out[(size_t)idx * 3 + 1] = e1 * r;
    out[(size_t)idx * 3 + 2] = e2 * r;
}

extern "C" void kernel_launch(void* const* d_in, const int* in_sizes, int n_in,
                              void* d_out, int out_size, void* d_ws, size_t ws_size,
                              hipStream_t stream) {
    (void)in_sizes; (void)n_in; (void)out_size; (void)ws_size;
    const int*    tokens = (const int*)d_in[0];
    const float2* emb    = (const float2*)d_in[1];
    const float* fw0_Wk = (const float*)d_in[2];
    const float* fw0_Wr = (const float*)d_in[3];
    const float* fw0_b  = (const float*)d_in[4];
    const float* fw1_Wk = (const float*)d_in[5];
    const float* fw1_Wr = (const float*)d_in[6];
    const float* fw1_b  = (const float*)d_in[7];
    const float* bw0_Wk = (const float*)d_in[8];
    const float* bw0_Wr = (const float*)d_in[9];
    const float* bw0_b  = (const float*)d_in[10];
    const float* bw1_Wk = (const float*)d_in[11];
    const float* bw1_Wr = (const float*)d_in[12];
    const float* bw1_b  = (const float*)d_in[13];
    const float* dW     = (const float*)d_in[14];
    const float* db     = (const float*)d_in[15];

    char* ws = (char*)d_ws;
    int*   cnt = (int*)(ws + OFF_CNT);
    u16*   H0  = (u16*)(ws + OFF_H0);
    u16*   H1  = (u16*)(ws + OFF_H1);
    float* lg  = (float*)(ws + OFF_LOG);
    u32*   Xw  = (u32*)(ws + OFF_X);
    const u16* Xr = (const u16*)(ws + OFF_X);
    u16*   Wg  = (u16*)(ws + OFF_W);
    const u16* Wgc = Wg;

    hipMemsetAsync(ws, 0, ZB, stream);
    embed_k<<<32768, 64, 0, stream>>>(tokens, emb, Xw);
    wrepack_k<<<5120, 256, 0, stream>>>(fw0_Wr, fw0_Wk, Wg + CB_FW0, 640);
    wrepack_k<<<8192, 256, 0, stream>>>(fw1_Wr, fw1_Wk, Wg + CB_FW1, 1024);
    wrepack_k<<<5120, 256, 0, stream>>>(bw0_Wr, bw0_Wk, Wg + CB_BW0, 640);
    wrepack_k<<<8192, 256, 0, stream>>>(bw1_Wr, bw1_Wk, Wg + CB_BW1, 1024);

    hipFuncSetAttribute((const void*)lstm_engine,
                        hipFuncAttributeMaxDynamicSharedMemorySize, SMEM_BYTES);
    void* args[] = { (void*)&Wgc, (void*)&Xr, (void*)&H0, (void*)&H1, (void*)&cnt,
                     (void*)&lg, (void*)&fw0_b, (void*)&fw1_b, (void*)&bw0_b,
                     (void*)&bw1_b, (void*)&dW };
    hipLaunchCooperativeKernel((const void*)lstm_engine, dim3(256), dim3(256),
                               args, SMEM_BYTES, stream);

    softmax_k<<<128, 256, 0, stream>>>(lg, db, (float*)d_out);
}

// Round 11
// 2457.403 us; speedup vs baseline: 1.1602x; 1.0537x over previous
//
#include <hip/hip_runtime.h>
#include <hip/hip_bf16.h>

typedef unsigned short u16;
typedef unsigned int u32;
typedef unsigned long long u64;
typedef __attribute__((ext_vector_type(8))) short s16x8;
typedef __attribute__((ext_vector_type(4))) float f32x4;

// ---------------- sizes ----------------
// B=128 S=256 E=128 U=512 C=3 ; float inputs are f32, converted to bf16 on device.
//  [0)        tags   : [2][2][256][2][32] int    = 262144  (per-WG publish tags)
//  [262144)   h0ring : [2][4][128][512] bf16     = 1048576 (natural row-major)
//  [1310720)  h1ring : [2][4][128][512] bf16     = 1048576
//  [2359296)  logits : [128][256][3] f32         = 393216
//  ZB = 2752512 (zeroed each launch)
//  [2752512)  X      : [256][128][128] bf16      = 8388608
//  [11141120) Wg     : packed bf16 weights       = 13762560
static constexpr size_t OFF_CNT = 0;
static constexpr size_t OFF_H0  = 262144;
static constexpr size_t OFF_H1  = OFF_H0 + 1048576;
static constexpr size_t OFF_LOG = OFF_H1 + 1048576;
static constexpr size_t ZB      = OFF_LOG + 393216;     // 2752512
static constexpr size_t OFF_X   = ZB;
static constexpr size_t OFF_W   = OFF_X + 8388608;      // 11141120
// packed weight chain offsets in elements (u16):
static constexpr size_t CB_FW0 = 0;
static constexpr size_t CB_FW1 = 1327104;   // 32*64*648
static constexpr size_t CB_BW0 = 3440640;
static constexpr size_t CB_BW1 = 4767744;
// LDS: weight strip (layer-1 worst case 132096B) + 4 waves * 512B transpose scratch
static constexpr unsigned SMEM_BYTES = 64 * 1032 * 2 + 4 * 512;   // 134144

__device__ inline u16 f2bu(float f) {
    union { float f; u32 u; } v; v.f = f;
    u32 x = v.u;
    return (u16)((x + 0x7fffu + ((x >> 16) & 1u)) >> 16);  // RNE f32->bf16
}
__device__ inline float sigf(float x) {
    x = fminf(fmaxf(x, -30.f), 30.f);
    return 1.f / (1.f + __expf(-x));
}
__device__ inline float tanh_f(float x) {
    x = fminf(fmaxf(x, -15.f), 15.f);
    float e = __expf(2.f * x);
    return (e - 1.f) / (e + 1.f);
}

// ---------------- phase A kernels ----------------
__global__ void embed_k(const int* __restrict__ tokens, const float2* __restrict__ emb,
                        u32* __restrict__ Xo) {
    int sb = blockIdx.x;               // s*128 + b
    int b = sb & 127, s = sb >> 7;
    int tok = tokens[b * 256 + s];
    float2 v = emb[(size_t)tok * 64 + threadIdx.x];
    Xo[(size_t)sb * 64 + threadIdx.x] = (u32)f2bu(v.x) | ((u32)f2bu(v.y) << 16);
}

// pack [Wr;Wk] (f32 -> bf16) column-reordered (strip-gate-major), +8 row pad.
// dst[nn*(Kc+8) + krow], nn = strip*64 + g*16 + u, src col = g*512 + strip*16 + u
__global__ void wrepack_k(const float* __restrict__ Wr, const float* __restrict__ Wk,
                          u16* __restrict__ dst, int Kc) {
    int e = blockIdx.x * 256 + threadIdx.x;
    int krow = e % Kc;
    int nn = e / Kc;
    if (nn >= 2048) return;
    int i = nn >> 6, n = nn & 63;
    int g = n >> 4, u = n & 15;
    int col = g * 512 + i * 16 + u;
    float v = (krow < 512) ? Wr[(size_t)krow * 2048 + col]
                           : Wk[(size_t)(krow - 512) * 2048 + col];
    dst[(size_t)nn * (Kc + 8) + krow] = f2bu(v);
}

// ---------------- main persistent kernel ----------------
// Protocol (round-11 — round-9 proven core + inv-every-4-steps):
//   WRITER: LDS transpose -> coalesced 8B sc0sc1 WRITE-THROUGH h store ->
//           vmcnt(0) -> barrier -> tid0 RELAXED tag store (uncontended).
//   READER: wave0 polls tag groups lane-parallel -> acquire agent fence
//           (buffer_inv) ONLY when (t&3)==0 -> plain cached batched loads.
//   WHY inv/4 is safe: a ring slot is re-read exactly 4 steps after its
//   previous read. The inv at the unique t≡0 (mod 4) inside each 4-step
//   window executes BEFORE that step's reads, killing the prior epoch's
//   lines. Any slot line re-allocated after that inv comes from L3 after the
//   new epoch's flag (writers are WT/no-allocate; readers touch a slot only
//   post-flag) -> fresh. Cuts whole-L2 invs from 32/XCD/step to 8/XCD/step
//   and lets X + fresh h lines survive across steps.
__device__ inline void wait_tags(const int* ta, const int* tb, bool doInv) {
    const int tid = threadIdx.x;
    if (tid < 64) {
        const int lane = tid;
        const int* mine = nullptr;
        if (lane < 32) { if (ta) mine = ta + lane; }
        else           { if (tb) mine = tb + (lane - 32); }
        bool done = (mine == nullptr);
        int spins = 0;
        for (;;) {
            if (!done)
                done = __hip_atomic_load(mine, __ATOMIC_RELAXED,
                                         __HIP_MEMORY_SCOPE_AGENT) != 0;
            if (__ballot(done) == ~0ull) break;
            __builtin_amdgcn_s_sleep(2);
            if (++spins > (1 << 17)) break;   // ~7 ms watchdog
        }
        if (doInv)
            __builtin_amdgcn_fence(__ATOMIC_ACQUIRE, "agent");   // inv only
    }
    __syncthreads();
}

template <int LAYER>
__device__ __forceinline__ void run_chain(
    const u16* __restrict__ wlds, u16* __restrict__ tlds, const u16* __restrict__ X,
    u16* __restrict__ H0, u16* __restrict__ H1, int* __restrict__ cb,
    float* __restrict__ logits, const float* __restrict__ bptr,
    const float* __restrict__ dW,
    int dir, int p, int strip, int wv, int lane)
{
    constexpr int Kpad = LAYER ? 1032 : 648;
    const int tid  = threadIdx.x;
    const int uu   = lane & 15;
    const int qq   = lane >> 4;
    const int rowA = p * 64 + wv * 16 + uu;
    const u16* blds = wlds + (size_t)uu * Kpad + qq * 8;

    float bias[4];
#pragma unroll
    for (int g = 0; g < 4; ++g) bias[g] = bptr[g * 512 + strip * 16 + uu];
    float wd[3] = {0.f, 0.f, 0.f};
    if (LAYER == 1) {
#pragma unroll
        for (int c = 0; c < 3; ++c)
            wd[c] = dW[(size_t)(dir * 512 + strip * 16 + uu) * 3 + c];
    }

    float cst[4] = {0.f, 0.f, 0.f, 0.f};

    for (int t = 0; t < 256; ++t) {
        s16x8 af[16], af2[16], xf[4];
        const bool doInv = ((t & 3) == 0);

        if (LAYER == 0) {
            // X prefetch into VGPRs BEFORE the wait (read-only; VGPR values
            // survive the occasional inv)
            int tx = dir ? (255 - t) : t;
            const u16* xb = X + (size_t)tx * 16384 + rowA * 128 + qq * 8;
#pragma unroll
            for (int j = 0; j < 4; ++j) xf[j] = *(const s16x8*)(xb + j * 32);

            // wait: h0[t-1] tag group + ring backpressure tag group (L1 t-4)
            const int* ta = (t > 0)  ? cb + (((t - 1) * 2 + p) << 5) : nullptr;
            const int* tb = (t >= 4) ? cb + (((256 + (t - 4)) * 2 + p) << 5) : nullptr;
            if (ta || tb) wait_tags(ta, tb, doInv);

            // batched plain loads of all 16 h0_prev fragments (one latency round)
            const u16* pa = H0 + ((t - 1) & 3) * 65536 + (size_t)rowA * 512 + qq * 8;
#pragma unroll
            for (int i = 0; i < 16; ++i) af[i] = *(const s16x8*)(pa + i * 32);
        } else {
            // wait: h0[t] tag group + h1[t-1] tag group
            const int* ta = cb + ((t * 2 + p) << 5);
            const int* tb = (t > 0) ? cb + (((256 + (t - 1)) * 2 + p) << 5) : nullptr;
            wait_tags(ta, tb, doInv);

            const u16* pb = H0 + (t & 3) * 65536 + (size_t)rowA * 512 + qq * 8;
#pragma unroll
            for (int i = 0; i < 16; ++i) af2[i] = *(const s16x8*)(pb + i * 32);
            const u16* pa = H1 + ((t - 1) & 3) * 65536 + (size_t)rowA * 512 + qq * 8;
#pragma unroll
            for (int i = 0; i < 16; ++i) af[i] = *(const s16x8*)(pa + i * 32);
        }

        f32x4 acc[4];
#pragma unroll
        for (int g = 0; g < 4; ++g)
            acc[g] = (f32x4){bias[g], bias[g], bias[g], bias[g]};

        // MFMA order identical to the proven kernels: kt ascending, gate inner
#pragma unroll
        for (int kt = 0; kt < 16; ++kt) {
            s16x8 av = af[kt];
#pragma unroll
            for (int g = 0; g < 4; ++g) {
                s16x8 bv = *(const s16x8*)(blds + (size_t)g * 16 * Kpad + kt * 32);
                acc[g] = __builtin_amdgcn_mfma_f32_16x16x32_bf16(av, bv, acc[g], 0, 0, 0);
            }
        }
        if (LAYER == 0) {
#pragma unroll
            for (int j = 0; j < 4; ++j) {
                s16x8 av = xf[j];
#pragma unroll
                for (int g = 0; g < 4; ++g) {
                    s16x8 bv = *(const s16x8*)(blds + (size_t)g * 16 * Kpad + (16 + j) * 32);
                    acc[g] = __builtin_amdgcn_mfma_f32_16x16x32_bf16(av, bv, acc[g], 0, 0, 0);
                }
            }
        } else {
#pragma unroll
            for (int kt = 0; kt < 16; ++kt) {
                s16x8 av = af2[kt];
#pragma unroll
                for (int g = 0; g < 4; ++g) {
                    s16x8 bv = *(const s16x8*)(blds + (size_t)g * 16 * Kpad + (16 + kt) * 32);
                    acc[g] = __builtin_amdgcn_mfma_f32_16x16x32_bf16(av, bv, acc[g], 0, 0, 0);
                }
            }
        }

        // LSTM epilogue
        u16* Hout = (LAYER == 0) ? H0 + (t & 3) * 65536 : H1 + (t & 3) * 65536;
        float hv[4];
        u32 hb[4];
#pragma unroll
        for (int j = 0; j < 4; ++j) {
            float iv = sigf(acc[0][j]);
            float fv = sigf(acc[1][j]);
            float gv = tanh_f(acc[2][j]);
            float ov = sigf(acc[3][j]);
            float cj = fv * cst[j] + iv * gv;
            cst[j] = cj;
            float h = ov * tanh_f(cj);
            hv[j] = h;
            hb[j] = (u32)f2bu(h);
        }

        // per-wave 16x16 u16 transpose through wave-private LDS scratch, then
        // ONE coalesced 8B write-through store per lane
        u16* tw = tlds + wv * 256;
#pragma unroll
        for (int j = 0; j < 4; ++j)
            tw[(qq * 4 + j) * 16 + uu] = (u16)hb[j];
        asm volatile("s_waitcnt lgkmcnt(0)" ::: "memory");
        __builtin_amdgcn_sched_barrier(0);
        {
            const int r  = lane >> 2;       // 0..15 row within wave tile
            const int cq = lane & 3;        // 4-col group
            u64 v = *(const u64*)(tw + r * 16 + cq * 4);
            u16* dst = Hout + (size_t)(p * 64 + wv * 16 + r) * 512 + strip * 16 + cq * 4;
            asm volatile("global_store_dwordx2 %0, %1, off sc0 sc1"
                         :: "v"(dst), "v"(v) : "memory");
        }

        // drain h stores, block barrier, then publish via UNCONTENDED tag store
        asm volatile("s_waitcnt vmcnt(0)" ::: "memory");
        __syncthreads();
        if (tid == 0)
            __hip_atomic_store(cb + (((LAYER * 256 + t) * 2 + p) << 5) + strip, 1,
                               __ATOMIC_RELAXED, __HIP_MEMORY_SCOPE_AGENT);

        if (LAYER == 1) {   // fused dense AFTER the publish: atomics drain in
                            // the background (consumed only by softmax_k)
            int s_out = dir ? (255 - t) : t;
            const int rowC = p * 64 + wv * 16 + qq * 4;
#pragma unroll
            for (int j = 0; j < 4; ++j) {
#pragma unroll
                for (int c = 0; c < 3; ++c) {
                    float v = hv[j] * wd[c];
                    v += __shfl_xor(v, 1);
                    v += __shfl_xor(v, 2);
                    v += __shfl_xor(v, 4);
                    v += __shfl_xor(v, 8);
                    if (uu == 0)
                        atomicAdd(&logits[((size_t)(rowC + j) * 256 + s_out) * 3 + c], v);
                }
            }
        }
    }
    // ensure trailing background atomics/stores are complete before endpgm
    asm volatile("s_waitcnt vmcnt(0)" ::: "memory");
}

__global__ void __launch_bounds__(256, 1)
lstm_engine(const u16* __restrict__ Wg, const u16* __restrict__ X,
            u16* __restrict__ h0ring, u16* __restrict__ h1ring,
            int* __restrict__ cnt, float* __restrict__ logits,
            const float* __restrict__ bf0, const float* __restrict__ bf1,
            const float* __restrict__ bb0, const float* __restrict__ bb1,
            const float* __restrict__ dW) {
    extern __shared__ u16 wlds[];
    const int tid = threadIdx.x;
    const int bid = blockIdx.x;
    const int dir   = bid >> 7;        // 0 fw, 1 bw
    const int rr    = bid & 127;
    const int layer = rr >> 6;         // 0 or 1
    const int q     = rr & 63;
    const int strip = q >> 1;          // 0..31 (16 hidden units each)
    const int p     = q & 1;           // row block (64 rows)
    const int wv    = tid >> 6;        // wave 0..3
    const int lane  = tid & 63;

    const int Kc   = layer ? 1024 : 640;
    const int Kpad = Kc + 8;
    const size_t cbase = layer ? (dir ? CB_BW1 : CB_FW1) : (dir ? CB_BW0 : CB_FW0);
    const u16* wsrc = Wg + cbase + (size_t)strip * 64 * Kpad;

    {   // stage weight strip into LDS (one time)
        const uint4* s4 = (const uint4*)wsrc;
        uint4* d4 = (uint4*)wlds;
        const int n16 = (64 * Kpad) / 8;
        for (int j = tid; j < n16; j += 256) d4[j] = s4[j];
    }
    __syncthreads();

    u16* tlds = wlds + (size_t)64 * Kpad;   // 4 waves x 512B transpose scratch

    u16* H0 = h0ring + (size_t)dir * (4 * 65536);
    u16* H1 = h1ring + (size_t)dir * (4 * 65536);
    int* cb = cnt + dir * (2 * 256 * 2 * 32);   // [layer][t][p][strip]
    const float* bptr = layer ? (dir ? bb1 : bf1) : (dir ? bb0 : bf0);

    if (layer == 0)
        run_chain<0>(wlds, tlds, X, H0, H1, cb, logits, bptr, dW, dir, p, strip, wv, lane);
    else
        run_chain<1>(wlds, tlds, X, H0, H1, cb, logits, bptr, dW, dir, p, strip, wv, lane);
}

__global__ void softmax_k(const float* __restrict__ logits, const float* __restrict__ db,
                          float* __restrict__ out) {
    int idx = blockIdx.x * 256 + threadIdx.x;   // b*256+s
    float l0 = logits[(size_t)idx * 3 + 0] + db[0];
    float l1 = logits[(size_t)idx * 3 + 1] + db[1];
    float l2 = logits[(size_t)idx * 3 + 2] + db[2];
    float m = fmaxf(l0, fmaxf(l1, l2));
    float e0 = __expf(l0 - m), e1 = __expf(l1 - m), e2 = __expf(l2 - m);
    float r = 1.f / (e0 + e1 + e2);
    out[(size_t)idx * 3 + 0] = e0 * r;
    out[(size_t)idx * 3 + 1] = e1 * r;
    out[(size_t)idx * 3 + 2] = e2 * r;
}

extern "C" void kernel_launch(void* const* d_in, const int* in_sizes, int n_in,
                              void* d_out, int out_size, void* d_ws, size_t ws_size,
                              hipStream_t stream) {
    (void)in_sizes; (void)n_in; (void)out_size; (void)ws_size;
    const int*    tokens = (const int*)d_in[0];
    const float2* emb    = (const float2*)d_in[1];
    const float* fw0_Wk = (const float*)d_in[2];
    const float* fw0_Wr = (const float*)d_in[3];
    const float* fw0_b  = (const float*)d_in[4];
    const float* fw1_Wk = (const float*)d_in[5];
    const float* fw1_Wr = (const float*)d_in[6];
    const float* fw1_b  = (const float*)d_in[7];
    const float* bw0_Wk = (const float*)d_in[8];
    const float* bw0_Wr = (const float*)d_in[9];
    const float* bw0_b  = (const float*)d_in[10];
    const float* bw1_Wk = (const float*)d_in[11];
    const float* bw1_Wr = (const float*)d_in[12];
    const float* bw1_b  = (const float*)d_in[13];
    const float* dW     = (const float*)d_in[14];
    const float* db     = (const float*)d_in[15];

    char* ws = (char*)d_ws;
    int*   cnt = (int*)(ws + OFF_CNT);
    u16*   H0  = (u16*)(ws + OFF_H0);
    u16*   H1  = (u16*)(ws + OFF_H1);
    float* lg  = (float*)(ws + OFF_LOG);
    u32*   Xw  = (u32*)(ws + OFF_X);
    const u16* Xr = (const u16*)(ws + OFF_X);
    u16*   Wg  = (u16*)(ws + OFF_W);
    const u16* Wgc = Wg;

    hipMemsetAsync(ws, 0, ZB, stream);
    embed_k<<<32768, 64, 0, stream>>>(tokens, emb, Xw);
    wrepack_k<<<5120, 256, 0, stream>>>(fw0_Wr, fw0_Wk, Wg + CB_FW0, 640);
    wrepack_k<<<8192, 256, 0, stream>>>(fw1_Wr, fw1_Wk, Wg + CB_FW1, 1024);
    wrepack_k<<<5120, 256, 0, stream>>>(bw0_Wr, bw0_Wk, Wg + CB_BW0, 640);
    wrepack_k<<<8192, 256, 0, stream>>>(bw1_Wr, bw1_Wk, Wg + CB_BW1, 1024);

    hipFuncSetAttribute((const void*)lstm_engine,
                        hipFuncAttributeMaxDynamicSharedMemorySize, SMEM_BYTES);
    void* args[] = { (void*)&Wgc, (void*)&Xr, (void*)&H0, (void*)&H1, (void*)&cnt,
                     (void*)&lg, (void*)&fw0_b, (void*)&fw1_b, (void*)&bw0_b,
                     (void*)&bw1_b, (void*)&dW };
    hipLaunchCooperativeKernel((const void*)lstm_engine, dim3(256), dim3(256),
                               args, SMEM_BYTES, stream);

    softmax_k<<<128, 256, 0, stream>>>(lg, db, (float*)d_out);
}